// Round 7
// baseline (77.280 us; speedup 1.0000x reference)
//
#include <hip/hip_runtime.h>
#include <hip/hip_bf16.h>

#define DMODEL 1024
#define DH 64
#define BB 4
#define SS 2048
#define NROW (BB * SS)   // 8192
#define NS 8             // kv-splits per q-tile

typedef __attribute__((ext_vector_type(8))) short bf16x8;
typedef __attribute__((ext_vector_type(4))) float f32x4;

__device__ __forceinline__ unsigned short f2bf(float f) {
    __hip_bfloat16 h = __float2bfloat16(f);
    return __builtin_bit_cast(unsigned short, h);
}

// ---------------- prep: Wt[192][1024] bf16 = [Wq|Wk|Wv]^T ----------------
__global__ __launch_bounds__(256) void prep_wt_kernel(
    const float* __restrict__ Wq, const float* __restrict__ Wk,
    const float* __restrict__ Wv, unsigned short* __restrict__ Wt)
{
    int idx = blockIdx.x * 256 + threadIdx.x;      // 0 .. 196607
    int m   = idx >> 16;                           // 0..2
    int rem = idx & 65535;
    int k   = rem >> 6;
    int n   = rem & 63;
    const float* W = (m == 0) ? Wq : (m == 1) ? Wk : Wv;
    float v = W[(size_t)k * DH + n];               // coalesced read
    Wt[(size_t)(m * 64 + n) * DMODEL + k] = f2bf(v);
}

// ---------------- QKV projection via MFMA, LDS-free ----------------
// one wave per block; wave owns 16 rows x 192 cols (12 MFMA tiles)
__global__ __launch_bounds__(64) void qkv_proj_mfma(
    const float* __restrict__ emb, const unsigned short* __restrict__ Wt,
    const float* __restrict__ bq, const float* __restrict__ bk,
    const float* __restrict__ bv,
    unsigned short* __restrict__ Q, unsigned short* __restrict__ K,
    unsigned short* __restrict__ V)
{
    const int lane = threadIdx.x;
    const int c    = lane & 15;
    const int g    = lane >> 4;         // 0..3
    const int row0 = blockIdx.x * 16;

    f32x4 acc[12];
    #pragma unroll
    for (int t = 0; t < 12; ++t) acc[t] = (f32x4){0.f, 0.f, 0.f, 0.f};

    // A-fragment row for this lane; per K-step lane needs fp32 elements
    // k0+32*kp+8*g .. +7 for kp=0,1  (16 floats = 4 float4)
    const float* arow = emb + (size_t)(row0 + c) * DMODEL;
    const int offs0 = 8 * g;           // kp=0 first half
    const int offs1 = 8 * g + 4;       // kp=0 second half
    const int offs2 = 32 + 8 * g;      // kp=1 first half
    const int offs3 = 32 + 8 * g + 4;  // kp=1 second half

    float4 f0 = *reinterpret_cast<const float4*>(arow + offs0);
    float4 f1 = *reinterpret_cast<const float4*>(arow + offs1);
    float4 f2 = *reinterpret_cast<const float4*>(arow + offs2);
    float4 f3 = *reinterpret_cast<const float4*>(arow + offs3);

    for (int k0 = 0; k0 < DMODEL; k0 += 64) {
        // convert current A regs fp32 -> bf16 fragments
        bf16x8 a[2];
        {
            union { bf16x8 v; unsigned short u[8]; } p0, p1;
            p0.u[0] = f2bf(f0.x); p0.u[1] = f2bf(f0.y);
            p0.u[2] = f2bf(f0.z); p0.u[3] = f2bf(f0.w);
            p0.u[4] = f2bf(f1.x); p0.u[5] = f2bf(f1.y);
            p0.u[6] = f2bf(f1.z); p0.u[7] = f2bf(f1.w);
            p1.u[0] = f2bf(f2.x); p1.u[1] = f2bf(f2.y);
            p1.u[2] = f2bf(f2.z); p1.u[3] = f2bf(f2.w);
            p1.u[4] = f2bf(f3.x); p1.u[5] = f2bf(f3.y);
            p1.u[6] = f2bf(f3.z); p1.u[7] = f2bf(f3.w);
            a[0] = p0.v; a[1] = p1.v;
        }
        // prefetch next K-step's A regs (issues before the MFMA block)
        const int k1 = k0 + 64;
        if (k1 < DMODEL) {
            f0 = *reinterpret_cast<const float4*>(arow + k1 + offs0);
            f1 = *reinterpret_cast<const float4*>(arow + k1 + offs1);
            f2 = *reinterpret_cast<const float4*>(arow + k1 + offs2);
            f3 = *reinterpret_cast<const float4*>(arow + k1 + offs3);
        }
        // 12 col-tiles x 2 k-halves; B streams from L2-resident Wt
        #pragma unroll
        for (int t = 0; t < 12; ++t) {
            const size_t brow = (size_t)(16 * t + c) * DMODEL + k0 + 8 * g;
            #pragma unroll
            for (int kp = 0; kp < 2; ++kp) {
                bf16x8 bfr = __builtin_bit_cast(bf16x8,
                    *reinterpret_cast<const uint4*>(&Wt[brow + 32 * kp]));
                acc[t] = __builtin_amdgcn_mfma_f32_16x16x32_bf16(a[kp], bfr, acc[t], 0, 0, 0);
            }
        }
    }

    // epilogue: bias (+ 1/8 scale folded into Q), store bf16
    #pragma unroll
    for (int t = 0; t < 12; ++t) {
        const int col = 16 * t + c;
        const int m   = col >> 6;
        const int lc  = col & 63;
        const float* bias = (m == 0) ? bq : (m == 1) ? bk : bv;
        unsigned short* O = (m == 0) ? Q : (m == 1) ? K : V;
        const float bs    = bias[lc];
        const float scale = (m == 0) ? 0.125f : 1.0f;
        #pragma unroll
        for (int i = 0; i < 4; ++i) {
            const int r = row0 + 4 * g + i;
            O[(size_t)r * DH + lc] = f2bf((acc[t][i] + bs) * scale);
        }
    }
}

// ---------------- causal flash attention via MFMA, KV-split ----------------
// grid (qt, b, s): block handles q-tile qt of batch b, k-tiles [kt0, kt1)
// writes UNNORMALIZED partials: Opart[s][row][d], mpart[s][row], lpart[s][row]
__global__ __launch_bounds__(256) void attn_mfma_split(
    const unsigned short* __restrict__ Q, const unsigned short* __restrict__ K,
    const unsigned short* __restrict__ V,
    float* __restrict__ Opart, float* __restrict__ mpart,
    float* __restrict__ lpart)
{
    __shared__ unsigned short Ks[64][72];      // [kv][d]
    __shared__ unsigned short Vt[64][72];      // [d][kv]  (transposed)
    __shared__ unsigned short Ps[4][16][72];   // per-wave P tile [qrow][kv]

    const int tid  = threadIdx.x;
    const int lane = tid & 63;
    const int w    = tid >> 6;
    const int c    = lane & 15;
    const int g    = lane >> 4;
    const int qt   = blockIdx.x;
    const int b    = blockIdx.y;
    const int sp   = blockIdx.z;
    const int q0   = qt * 64;

    const int ntile = qt + 1;
    const int kt0 = (ntile * sp) / NS;
    const int kt1 = (ntile * (sp + 1)) / NS;

    const unsigned short* Qb = Q + (size_t)b * SS * DH;
    const unsigned short* Kb = K + (size_t)b * SS * DH;
    const unsigned short* Vb = V + (size_t)b * SS * DH;

    // Q fragments, register resident (scale 1/8 already folded in)
    bf16x8 qa[2];
    #pragma unroll
    for (int kp = 0; kp < 2; ++kp)
        qa[kp] = __builtin_bit_cast(bf16x8,
            *reinterpret_cast<const uint4*>(
                &Qb[(size_t)(q0 + 16 * w + c) * DH + 32 * kp + 8 * g]));

    f32x4 o[4];
    #pragma unroll
    for (int t = 0; t < 4; ++t) o[t] = (f32x4){0.f, 0.f, 0.f, 0.f};
    float m_i[4] = {-1e30f, -1e30f, -1e30f, -1e30f};
    float l_i[4] = {0.f, 0.f, 0.f, 0.f};

    for (int kt = kt0; kt < kt1; ++kt) {
        const int kb0 = kt * 64;
        __syncthreads();   // prior tile's LDS reads done
        // stage K (row-major) and V (transposed), 2 x 16B per thread each
        #pragma unroll
        for (int j = 0; j < 2; ++j) {
            const int idx = tid + 256 * j;
            const int kv  = idx >> 3;
            const int d0  = (idx & 7) * 8;
            *reinterpret_cast<uint4*>(&Ks[kv][d0]) =
                *reinterpret_cast<const uint4*>(&Kb[(size_t)(kb0 + kv) * DH + d0]);
            const uint4 vv =
                *reinterpret_cast<const uint4*>(&Vb[(size_t)(kb0 + kv) * DH + d0]);
            const unsigned wd[4] = {vv.x, vv.y, vv.z, vv.w};
            #pragma unroll
            for (int e = 0; e < 8; ++e)
                Vt[d0 + e][kv] = (unsigned short)(wd[e >> 1] >> (16 * (e & 1)));
        }
        __syncthreads();

        // S = Q Ktile^T  (4 col-tiles x 2 k-steps)
        f32x4 s[4];
        #pragma unroll
        for (int t = 0; t < 4; ++t) s[t] = (f32x4){0.f, 0.f, 0.f, 0.f};
        #pragma unroll
        for (int t = 0; t < 4; ++t)
            #pragma unroll
            for (int kp = 0; kp < 2; ++kp) {
                bf16x8 kf = __builtin_bit_cast(bf16x8,
                    *reinterpret_cast<const uint4*>(&Ks[16 * t + c][32 * kp + 8 * g]));
                s[t] = __builtin_amdgcn_mfma_f32_16x16x32_bf16(qa[kp], kf, s[t], 0, 0, 0);
            }

        // causal mask (only the diagonal tile needs it)
        if (kt == qt) {
            #pragma unroll
            for (int t = 0; t < 4; ++t)
                #pragma unroll
                for (int i = 0; i < 4; ++i)
                    if (16 * t + c > 16 * w + 4 * g + i) s[t][i] = -1e30f;
        }

        // wave-parallel online softmax; quarter-wave owns q-rows 4g..4g+3 (i)
        float al[4];
        #pragma unroll
        for (int i = 0; i < 4; ++i) {
            float v = fmaxf(fmaxf(s[0][i], s[1][i]), fmaxf(s[2][i], s[3][i]));
            v = fmaxf(v, __shfl_xor(v, 1));
            v = fmaxf(v, __shfl_xor(v, 2));
            v = fmaxf(v, __shfl_xor(v, 4));
            v = fmaxf(v, __shfl_xor(v, 8));
            const float mn = fmaxf(m_i[i], v);
            al[i] = __expf(m_i[i] - mn);
            m_i[i] = mn;
        }
        #pragma unroll
        for (int t = 0; t < 4; ++t)
            #pragma unroll
            for (int i = 0; i < 4; ++i)
                s[t][i] = __expf(s[t][i] - m_i[i]);
        #pragma unroll
        for (int i = 0; i < 4; ++i) {
            float r = s[0][i] + s[1][i] + s[2][i] + s[3][i];
            r += __shfl_xor(r, 1);
            r += __shfl_xor(r, 2);
            r += __shfl_xor(r, 4);
            r += __shfl_xor(r, 8);
            l_i[i] = l_i[i] * al[i] + r;
        }

        // P -> per-wave LDS (reshape to A-fragment layout)
        #pragma unroll
        for (int t = 0; t < 4; ++t)
            #pragma unroll
            for (int i = 0; i < 4; ++i)
                Ps[w][4 * g + i][16 * t + c] = f2bf(s[t][i]);

        // rescale O
        #pragma unroll
        for (int t = 0; t < 4; ++t)
            #pragma unroll
            for (int i = 0; i < 4; ++i)
                o[t][i] *= al[i];

        // O += P Vtile   (A = P from LDS, B = V from transposed LDS)
        #pragma unroll
        for (int kp = 0; kp < 2; ++kp) {
            bf16x8 pa = __builtin_bit_cast(bf16x8,
                *reinterpret_cast<const uint4*>(&Ps[w][c][32 * kp + 8 * g]));
            #pragma unroll
            for (int t = 0; t < 4; ++t) {
                bf16x8 vf = __builtin_bit_cast(bf16x8,
                    *reinterpret_cast<const uint4*>(&Vt[16 * t + c][32 * kp + 8 * g]));
                o[t] = __builtin_amdgcn_mfma_f32_16x16x32_bf16(pa, vf, o[t], 0, 0, 0);
            }
        }
    }

    // epilogue: unnormalized partials
    const int rowbase = b * SS + q0 + 16 * w;
    #pragma unroll
    for (int t = 0; t < 4; ++t)
        #pragma unroll
        for (int i = 0; i < 4; ++i)
            Opart[((size_t)sp * NROW + rowbase + 4 * g + i) * DH + 16 * t + c] = o[t][i];
    if (c == 0) {
        #pragma unroll
        for (int i = 0; i < 4; ++i) {
            mpart[(size_t)sp * NROW + rowbase + 4 * g + i] = m_i[i];
            lpart[(size_t)sp * NROW + rowbase + 4 * g + i] = l_i[i];
        }
    }
}

// ---------------- combine partials ----------------
__global__ __launch_bounds__(256) void attn_combine(
    const float* __restrict__ Opart, const float* __restrict__ mpart,
    const float* __restrict__ lpart, float* __restrict__ out)
{
    const int idx = blockIdx.x * 256 + threadIdx.x;   // row*16 + d4
    const int row = idx >> 4;
    const int d4  = (idx & 15) * 4;

    float m[NS];
    float M = -1e30f;
    #pragma unroll
    for (int s = 0; s < NS; ++s) {
        m[s] = mpart[(size_t)s * NROW + row];
        M = fmaxf(M, m[s]);
    }
    float L = 0.f;
    float4 acc = {0.f, 0.f, 0.f, 0.f};
    #pragma unroll
    for (int s = 0; s < NS; ++s) {
        const float wgt = __expf(m[s] - M);
        L += wgt * lpart[(size_t)s * NROW + row];
        const float4 p = *reinterpret_cast<const float4*>(
            &Opart[((size_t)s * NROW + row) * DH + d4]);
        acc.x += wgt * p.x; acc.y += wgt * p.y;
        acc.z += wgt * p.z; acc.w += wgt * p.w;
    }
    const float inv = 1.f / L;
    float4 r = {acc.x * inv, acc.y * inv, acc.z * inv, acc.w * inv};
    *reinterpret_cast<float4*>(&out[(size_t)row * DH + d4]) = r;
}

extern "C" void kernel_launch(void* const* d_in, const int* in_sizes, int n_in,
                              void* d_out, int out_size, void* d_ws, size_t ws_size,
                              hipStream_t stream) {
    const float* emb = (const float*)d_in[0];
    const float* Wq  = (const float*)d_in[1];
    const float* bq  = (const float*)d_in[2];
    const float* Wk  = (const float*)d_in[3];
    const float* bk  = (const float*)d_in[4];
    const float* Wv  = (const float*)d_in[5];
    const float* bv  = (const float*)d_in[6];
    float* out = (float*)d_out;

    unsigned short* Qw = (unsigned short*)d_ws;
    unsigned short* Kw = Qw + (size_t)NROW * DH;
    unsigned short* Vw = Kw + (size_t)NROW * DH;
    unsigned short* Wt = Vw + (size_t)NROW * DH;          // 192*1024 bf16
    float* Opart = (float*)(Wt + (size_t)192 * DMODEL);   // [NS][NROW][DH] f32
    float* mpart = Opart + (size_t)NS * NROW * DH;        // [NS][NROW]
    float* lpart = mpart + (size_t)NS * NROW;             // [NS][NROW]

    hipLaunchKernelGGL(prep_wt_kernel, dim3(768), dim3(256), 0, stream,
                       Wq, Wk, Wv, Wt);
    hipLaunchKernelGGL(qkv_proj_mfma, dim3(NROW / 16), dim3(64), 0, stream,
                       emb, Wt, bq, bk, bv, Qw, Kw, Vw);
    hipLaunchKernelGGL(attn_mfma_split, dim3(SS / 64, BB, NS), dim3(256), 0, stream,
                       Qw, Kw, Vw, Opart, mpart, lpart);
    hipLaunchKernelGGL(attn_combine, dim3(NROW * 16 / 256), dim3(256), 0, stream,
                       Opart, mpart, lpart, out);
}

// Round 8
// 64.355 us; speedup vs baseline: 1.2008x; 1.2008x over previous
//
#include <hip/hip_runtime.h>
#include <hip/hip_bf16.h>

#define DMODEL 1024
#define DH 64
#define BB 4
#define SS 2048
#define NROW (BB * SS)   // 8192
#define NS 8             // kv-splits per q-tile

typedef __attribute__((ext_vector_type(8))) short bf16x8;
typedef __attribute__((ext_vector_type(4))) float f32x4;

__device__ __forceinline__ unsigned short f2bf(float f) {
    __hip_bfloat16 h = __float2bfloat16(f);
    return __builtin_bit_cast(unsigned short, h);
}

// ---------------- prep: Wt[192][1024] bf16 = [Wq|Wk|Wv]^T ----------------
__global__ __launch_bounds__(256) void prep_wt_kernel(
    const float* __restrict__ Wq, const float* __restrict__ Wk,
    const float* __restrict__ Wv, unsigned short* __restrict__ Wt)
{
    int idx = blockIdx.x * 256 + threadIdx.x;      // 0 .. 196607
    int m   = idx >> 16;                           // 0..2
    int rem = idx & 65535;
    int k   = rem >> 6;
    int n   = rem & 63;
    const float* W = (m == 0) ? Wq : (m == 1) ? Wk : Wv;
    float v = W[(size_t)k * DH + n];               // coalesced read
    Wt[(size_t)(m * 64 + n) * DMODEL + k] = f2bf(v);
}

// ---------------- QKV projection via MFMA ----------------
// 16 rows x 192 cols per block; 4 waves, wave w -> cols 48w..48w+47 (3 tiles)
// double-buffered LDS + 2-deep register prefetch of the A tile.
__global__ __launch_bounds__(256) void qkv_proj_mfma(
    const float* __restrict__ emb, const unsigned short* __restrict__ Wt,
    const float* __restrict__ bq, const float* __restrict__ bk,
    const float* __restrict__ bv,
    unsigned short* __restrict__ Q, unsigned short* __restrict__ K,
    unsigned short* __restrict__ V)
{
    __shared__ unsigned short A_lds[2][16][72];

    const int tid  = threadIdx.x;
    const int lane = tid & 63;
    const int w    = tid >> 6;          // wave 0..3
    const int c    = lane & 15;
    const int g    = lane >> 4;         // 0..3
    const int row0 = blockIdx.x * 16;

    f32x4 acc[3];
    #pragma unroll
    for (int t = 0; t < 3; ++t) acc[t] = (f32x4){0.f, 0.f, 0.f, 0.f};

    const int sr  = tid >> 4;           // staging row 0..15
    const int sc4 = tid & 15;           // staging float4 col
    const float* src = emb + (size_t)(row0 + sr) * DMODEL + sc4 * 4;

    // 2-deep prefetch: rA holds tile k, rB holds tile k+64 (coalesced float4)
    float4 rA = *reinterpret_cast<const float4*>(src);
    float4 rB = *reinterpret_cast<const float4*>(src + 64);

    #pragma unroll 2
    for (int k0 = 0; k0 < DMODEL; k0 += 128) {
        // ===== even tile (k0), buffer 0, regs rA =====
        {
            uint2 pk;
            pk.x = (unsigned)f2bf(rA.x) | ((unsigned)f2bf(rA.y) << 16);
            pk.y = (unsigned)f2bf(rA.z) | ((unsigned)f2bf(rA.w) << 16);
            *reinterpret_cast<uint2*>(&A_lds[0][sr][sc4 * 4]) = pk;
            if (k0 + 128 < DMODEL)
                rA = *reinterpret_cast<const float4*>(src + k0 + 128);
            __syncthreads();
            bf16x8 a0 = __builtin_bit_cast(bf16x8,
                *reinterpret_cast<const uint4*>(&A_lds[0][c][8 * g]));
            bf16x8 a1 = __builtin_bit_cast(bf16x8,
                *reinterpret_cast<const uint4*>(&A_lds[0][c][32 + 8 * g]));
            #pragma unroll
            for (int t = 0; t < 3; ++t) {
                const size_t brow = (size_t)(48 * w + 16 * t + c) * DMODEL + k0 + 8 * g;
                bf16x8 b0 = __builtin_bit_cast(bf16x8,
                    *reinterpret_cast<const uint4*>(&Wt[brow]));
                bf16x8 b1 = __builtin_bit_cast(bf16x8,
                    *reinterpret_cast<const uint4*>(&Wt[brow + 32]));
                acc[t] = __builtin_amdgcn_mfma_f32_16x16x32_bf16(a0, b0, acc[t], 0, 0, 0);
                acc[t] = __builtin_amdgcn_mfma_f32_16x16x32_bf16(a1, b1, acc[t], 0, 0, 0);
            }
        }
        // ===== odd tile (k0+64), buffer 1, regs rB =====
        {
            uint2 pk;
            pk.x = (unsigned)f2bf(rB.x) | ((unsigned)f2bf(rB.y) << 16);
            pk.y = (unsigned)f2bf(rB.z) | ((unsigned)f2bf(rB.w) << 16);
            *reinterpret_cast<uint2*>(&A_lds[1][sr][sc4 * 4]) = pk;
            if (k0 + 192 < DMODEL)
                rB = *reinterpret_cast<const float4*>(src + k0 + 192);
            __syncthreads();
            bf16x8 a0 = __builtin_bit_cast(bf16x8,
                *reinterpret_cast<const uint4*>(&A_lds[1][c][8 * g]));
            bf16x8 a1 = __builtin_bit_cast(bf16x8,
                *reinterpret_cast<const uint4*>(&A_lds[1][c][32 + 8 * g]));
            #pragma unroll
            for (int t = 0; t < 3; ++t) {
                const size_t brow = (size_t)(48 * w + 16 * t + c) * DMODEL + k0 + 64 + 8 * g;
                bf16x8 b0 = __builtin_bit_cast(bf16x8,
                    *reinterpret_cast<const uint4*>(&Wt[brow]));
                bf16x8 b1 = __builtin_bit_cast(bf16x8,
                    *reinterpret_cast<const uint4*>(&Wt[brow + 32]));
                acc[t] = __builtin_amdgcn_mfma_f32_16x16x32_bf16(a0, b0, acc[t], 0, 0, 0);
                acc[t] = __builtin_amdgcn_mfma_f32_16x16x32_bf16(a1, b1, acc[t], 0, 0, 0);
            }
        }
    }

    // epilogue: bias (+ 1/8 scale folded into Q), store bf16
    #pragma unroll
    for (int t = 0; t < 3; ++t) {
        const int col = 48 * w + 16 * t + c;
        const int m   = col >> 6;
        const int lc  = col & 63;
        const float* bias = (m == 0) ? bq : (m == 1) ? bk : bv;
        unsigned short* O = (m == 0) ? Q : (m == 1) ? K : V;
        const float bs    = bias[lc];
        const float scale = (m == 0) ? 0.125f : 1.0f;
        #pragma unroll
        for (int i = 0; i < 4; ++i) {
            const int r = row0 + 4 * g + i;
            O[(size_t)r * DH + lc] = f2bf((acc[t][i] + bs) * scale);
        }
    }
}

// ---------------- causal flash attention via MFMA, KV-split ----------------
// grid (qt, b, s): block handles q-tile qt of batch b, k-tiles [kt0, kt1)
// writes UNNORMALIZED partials: Opart[s][row][d], mpart[s][row], lpart[s][row]
__global__ __launch_bounds__(256) void attn_mfma_split(
    const unsigned short* __restrict__ Q, const unsigned short* __restrict__ K,
    const unsigned short* __restrict__ V,
    float* __restrict__ Opart, float* __restrict__ mpart,
    float* __restrict__ lpart)
{
    __shared__ unsigned short Ks[64][72];      // [kv][d]
    __shared__ unsigned short Vt[64][72];      // [d][kv]  (transposed)
    __shared__ unsigned short Ps[4][16][72];   // per-wave P tile [qrow][kv]

    const int tid  = threadIdx.x;
    const int lane = tid & 63;
    const int w    = tid >> 6;
    const int c    = lane & 15;
    const int g    = lane >> 4;
    const int qt   = blockIdx.x;
    const int b    = blockIdx.y;
    const int sp   = blockIdx.z;
    const int q0   = qt * 64;

    const int ntile = qt + 1;
    const int kt0 = (ntile * sp) / NS;
    const int kt1 = (ntile * (sp + 1)) / NS;

    const unsigned short* Qb = Q + (size_t)b * SS * DH;
    const unsigned short* Kb = K + (size_t)b * SS * DH;
    const unsigned short* Vb = V + (size_t)b * SS * DH;

    // Q fragments, register resident (scale 1/8 already folded in)
    bf16x8 qa[2];
    #pragma unroll
    for (int kp = 0; kp < 2; ++kp)
        qa[kp] = __builtin_bit_cast(bf16x8,
            *reinterpret_cast<const uint4*>(
                &Qb[(size_t)(q0 + 16 * w + c) * DH + 32 * kp + 8 * g]));

    f32x4 o[4];
    #pragma unroll
    for (int t = 0; t < 4; ++t) o[t] = (f32x4){0.f, 0.f, 0.f, 0.f};
    float m_i[4] = {-1e30f, -1e30f, -1e30f, -1e30f};
    float l_i[4] = {0.f, 0.f, 0.f, 0.f};

    for (int kt = kt0; kt < kt1; ++kt) {
        const int kb0 = kt * 64;
        __syncthreads();   // prior tile's LDS reads done
        // stage K (row-major) and V (transposed), 2 x 16B per thread each
        #pragma unroll
        for (int j = 0; j < 2; ++j) {
            const int idx = tid + 256 * j;
            const int kv  = idx >> 3;
            const int d0  = (idx & 7) * 8;
            *reinterpret_cast<uint4*>(&Ks[kv][d0]) =
                *reinterpret_cast<const uint4*>(&Kb[(size_t)(kb0 + kv) * DH + d0]);
            const uint4 vv =
                *reinterpret_cast<const uint4*>(&Vb[(size_t)(kb0 + kv) * DH + d0]);
            const unsigned wd[4] = {vv.x, vv.y, vv.z, vv.w};
            #pragma unroll
            for (int e = 0; e < 8; ++e)
                Vt[d0 + e][kv] = (unsigned short)(wd[e >> 1] >> (16 * (e & 1)));
        }
        __syncthreads();

        // S = Q Ktile^T  (4 col-tiles x 2 k-steps)
        f32x4 s[4];
        #pragma unroll
        for (int t = 0; t < 4; ++t) s[t] = (f32x4){0.f, 0.f, 0.f, 0.f};
        #pragma unroll
        for (int t = 0; t < 4; ++t)
            #pragma unroll
            for (int kp = 0; kp < 2; ++kp) {
                bf16x8 kf = __builtin_bit_cast(bf16x8,
                    *reinterpret_cast<const uint4*>(&Ks[16 * t + c][32 * kp + 8 * g]));
                s[t] = __builtin_amdgcn_mfma_f32_16x16x32_bf16(qa[kp], kf, s[t], 0, 0, 0);
            }

        // causal mask (only the diagonal tile needs it)
        if (kt == qt) {
            #pragma unroll
            for (int t = 0; t < 4; ++t)
                #pragma unroll
                for (int i = 0; i < 4; ++i)
                    if (16 * t + c > 16 * w + 4 * g + i) s[t][i] = -1e30f;
        }

        // wave-parallel online softmax; quarter-wave owns q-rows 4g..4g+3 (i)
        float al[4];
        #pragma unroll
        for (int i = 0; i < 4; ++i) {
            float v = fmaxf(fmaxf(s[0][i], s[1][i]), fmaxf(s[2][i], s[3][i]));
            v = fmaxf(v, __shfl_xor(v, 1));
            v = fmaxf(v, __shfl_xor(v, 2));
            v = fmaxf(v, __shfl_xor(v, 4));
            v = fmaxf(v, __shfl_xor(v, 8));
            const float mn = fmaxf(m_i[i], v);
            al[i] = __expf(m_i[i] - mn);
            m_i[i] = mn;
        }
        #pragma unroll
        for (int t = 0; t < 4; ++t)
            #pragma unroll
            for (int i = 0; i < 4; ++i)
                s[t][i] = __expf(s[t][i] - m_i[i]);
        #pragma unroll
        for (int i = 0; i < 4; ++i) {
            float r = s[0][i] + s[1][i] + s[2][i] + s[3][i];
            r += __shfl_xor(r, 1);
            r += __shfl_xor(r, 2);
            r += __shfl_xor(r, 4);
            r += __shfl_xor(r, 8);
            l_i[i] = l_i[i] * al[i] + r;
        }

        // P -> per-wave LDS (reshape to A-fragment layout)
        #pragma unroll
        for (int t = 0; t < 4; ++t)
            #pragma unroll
            for (int i = 0; i < 4; ++i)
                Ps[w][4 * g + i][16 * t + c] = f2bf(s[t][i]);

        // rescale O
        #pragma unroll
        for (int t = 0; t < 4; ++t)
            #pragma unroll
            for (int i = 0; i < 4; ++i)
                o[t][i] *= al[i];

        // O += P Vtile   (A = P from LDS, B = V from transposed LDS)
        #pragma unroll
        for (int kp = 0; kp < 2; ++kp) {
            bf16x8 pa = __builtin_bit_cast(bf16x8,
                *reinterpret_cast<const uint4*>(&Ps[w][c][32 * kp + 8 * g]));
            #pragma unroll
            for (int t = 0; t < 4; ++t) {
                bf16x8 vf = __builtin_bit_cast(bf16x8,
                    *reinterpret_cast<const uint4*>(&Vt[16 * t + c][32 * kp + 8 * g]));
                o[t] = __builtin_amdgcn_mfma_f32_16x16x32_bf16(pa, vf, o[t], 0, 0, 0);
            }
        }
    }

    // epilogue: unnormalized partials
    const int rowbase = b * SS + q0 + 16 * w;
    #pragma unroll
    for (int t = 0; t < 4; ++t)
        #pragma unroll
        for (int i = 0; i < 4; ++i)
            Opart[((size_t)sp * NROW + rowbase + 4 * g + i) * DH + 16 * t + c] = o[t][i];
    if (c == 0) {
        #pragma unroll
        for (int i = 0; i < 4; ++i) {
            mpart[(size_t)sp * NROW + rowbase + 4 * g + i] = m_i[i];
            lpart[(size_t)sp * NROW + rowbase + 4 * g + i] = l_i[i];
        }
    }
}

// ---------------- combine partials ----------------
__global__ __launch_bounds__(256) void attn_combine(
    const float* __restrict__ Opart, const float* __restrict__ mpart,
    const float* __restrict__ lpart, float* __restrict__ out)
{
    const int idx = blockIdx.x * 256 + threadIdx.x;   // row*16 + d4
    const int row = idx >> 4;
    const int d4  = (idx & 15) * 4;

    float m[NS];
    float M = -1e30f;
    #pragma unroll
    for (int s = 0; s < NS; ++s) {
        m[s] = mpart[(size_t)s * NROW + row];
        M = fmaxf(M, m[s]);
    }
    float L = 0.f;
    float4 acc = {0.f, 0.f, 0.f, 0.f};
    #pragma unroll
    for (int s = 0; s < NS; ++s) {
        const float wgt = __expf(m[s] - M);
        L += wgt * lpart[(size_t)s * NROW + row];
        const float4 p = *reinterpret_cast<const float4*>(
            &Opart[((size_t)s * NROW + row) * DH + d4]);
        acc.x += wgt * p.x; acc.y += wgt * p.y;
        acc.z += wgt * p.z; acc.w += wgt * p.w;
    }
    const float inv = 1.f / L;
    float4 r = {acc.x * inv, acc.y * inv, acc.z * inv, acc.w * inv};
    *reinterpret_cast<float4*>(&out[(size_t)row * DH + d4]) = r;
}

extern "C" void kernel_launch(void* const* d_in, const int* in_sizes, int n_in,
                              void* d_out, int out_size, void* d_ws, size_t ws_size,
                              hipStream_t stream) {
    const float* emb = (const float*)d_in[0];
    const float* Wq  = (const float*)d_in[1];
    const float* bq  = (const float*)d_in[2];
    const float* Wk  = (const float*)d_in[3];
    const float* bk  = (const float*)d_in[4];
    const float* Wv  = (const float*)d_in[5];
    const float* bv  = (const float*)d_in[6];
    float* out = (float*)d_out;

    unsigned short* Qw = (unsigned short*)d_ws;
    unsigned short* Kw = Qw + (size_t)NROW * DH;
    unsigned short* Vw = Kw + (size_t)NROW * DH;
    unsigned short* Wt = Vw + (size_t)NROW * DH;          // 192*1024 bf16
    float* Opart = (float*)(Wt + (size_t)192 * DMODEL);   // [NS][NROW][DH] f32
    float* mpart = Opart + (size_t)NS * NROW * DH;        // [NS][NROW]
    float* lpart = mpart + (size_t)NS * NROW;             // [NS][NROW]

    hipLaunchKernelGGL(prep_wt_kernel, dim3(768), dim3(256), 0, stream,
                       Wq, Wk, Wv, Wt);
    hipLaunchKernelGGL(qkv_proj_mfma, dim3(NROW / 16), dim3(256), 0, stream,
                       emb, Wt, bq, bk, bv, Qw, Kw, Vw);
    hipLaunchKernelGGL(attn_mfma_split, dim3(SS / 64, BB, NS), dim3(256), 0, stream,
                       Qw, Kw, Vw, Opart, mpart, lpart);
    hipLaunchKernelGGL(attn_combine, dim3(NROW * 16 / 256), dim3(256), 0, stream,
                       Opart, mpart, lpart, out);
}